// Round 2
// baseline (533.475 us; speedup 1.0000x reference)
//
#include <hip/hip_runtime.h>

#define HID 32
#define SEQ 512
#define WAVES_PER_BLOCK 4
#define BLOCK (WAVES_PER_BLOCK * 64)

// broadcast lane `lane`'s value of v to all lanes via v_readlane (VALU pipe,
// result lands in SGPR and feeds FMA's scalar operand slot — no ds_bpermute)
__device__ __forceinline__ float bcastlane(float v, int lane) {
    return __int_as_float(__builtin_amdgcn_readlane(__float_as_int(v), lane));
}

#define LOG2E  1.4426950408889634f
#define LOG2E2 2.8853900817779268f

__global__ __launch_bounds__(BLOCK, 4) void lstm_fused_kernel(
    const float* __restrict__ x,       // [B, T, 1]
    const float* __restrict__ W_ih,    // [4H, 1]
    const float* __restrict__ W_hh,    // [4H, H] row-major
    const float* __restrict__ b_ih,    // [4H]
    const float* __restrict__ b_hh,    // [4H]
    const float* __restrict__ W_head,  // [1, H]
    const float* __restrict__ b_head,  // [1]
    float* __restrict__ out)           // [B, 1]
{
    const int tid  = threadIdx.x;
    const int lane = tid & 63;
    const int k    = lane & 31;   // hidden unit owned by this lane
    const int p    = lane >> 5;   // 0: gates (i,f)   1: gates (g,o)
    const int wave = tid >> 6;
    const int b    = blockIdx.x * WAVES_PER_BLOCK + wave;  // one batch per wave

    const int rowA = 64 * p + k;       // i-row (p=0) or g-row (p=1)
    const int rowB = 64 * p + 32 + k;  // f-row (p=0) or o-row (p=1)

    // Weight rows in VGPRs: 64 regs/lane (fits 128-VGPR budget @ 4 waves/SIMD)
    float wA[HID], wB[HID];
    {
        const float4* WA = (const float4*)(W_hh + rowA * HID);
        const float4* WB = (const float4*)(W_hh + rowB * HID);
#pragma unroll
        for (int q = 0; q < HID / 4; ++q) {
            float4 a = WA[q], bb = WB[q];
            wA[4*q+0] = a.x;  wA[4*q+1] = a.y;  wA[4*q+2] = a.z;  wA[4*q+3] = a.w;
            wB[4*q+0] = bb.x; wB[4*q+1] = bb.y; wB[4*q+2] = bb.z; wB[4*q+3] = bb.w;
        }
    }

    const float biasA = b_ih[rowA] + b_hh[rowA];
    const float biasB = b_ih[rowB] + b_hh[rowB];
    const float uA = W_ih[rowA];
    const float uB = W_ih[rowB];

    // unified activation f(x) = 1 - m * rcp(1 + exp2(s*x)):
    //   sigmoid: m=1, s=log2(e)     tanh: m=2, s=2*log2(e)
    const float mA = p ? 2.0f   : 1.0f;
    const float sA = p ? LOG2E2 : LOG2E;

    const float* xb = x + (size_t)b * SEQ;  // I == 1

    float h = 0.0f, c = 0.0f;

    for (int t = 0; t < SEQ; ++t) {
        const float xt = xb[t];  // wave-uniform -> scalar load
        float pA = __builtin_fmaf(xt, uA, biasA);
        float pB = __builtin_fmaf(xt, uB, biasB);
#pragma unroll
        for (int j = 0; j < HID; ++j) {
            const float hj = bcastlane(h, j);  // h replicated across halves
            pA = __builtin_fmaf(hj, wA[j], pA);
            pB = __builtin_fmaf(hj, wB[j], pB);
        }
        // actA: sigmoid(pA) on p=0 (i-gate), tanh(pA) on p=1 (g-gate)
        const float eA   = __builtin_amdgcn_exp2f(sA * pA);
        const float actA = __builtin_fmaf(-mA, __builtin_amdgcn_rcpf(1.0f + eA), 1.0f);
        // actB: sigmoid(pB) on both halves (f-gate / o-gate)
        const float eB   = __builtin_amdgcn_exp2f(LOG2E * pB);
        const float actB = __builtin_fmaf(-1.0f, __builtin_amdgcn_rcpf(1.0f + eB), 1.0f);

        // exchange between halves: p=0 holds (i,f), p=1 holds (g,o)
        const float otherA = __shfl_xor(actA, 32);  // i<->g
        const float otherB = __shfl_xor(actB, 32);  // f<->o
        const float fg = p ? otherB : actB;  // forget gate
        const float og = p ? actB : otherB;  // output gate

        // i*g is actA*otherA on BOTH halves
        c = __builtin_fmaf(fg, c, actA * otherA);
        const float ec = __builtin_amdgcn_exp2f(LOG2E2 * c);
        const float tc = __builtin_fmaf(-2.0f, __builtin_amdgcn_rcpf(1.0f + ec), 1.0f);
        h = og * tc;  // replicated across halves
    }

    // head: out[b] = sum_k h[k]*W_head[k] + b_head  (mask p=1 half to avoid 2x)
    float v = h * (p ? 0.0f : W_head[k]);
#pragma unroll
    for (int off = 32; off >= 1; off >>= 1)
        v += __shfl_xor(v, off);
    if (lane == 0) out[b] = v + b_head[0];
}

extern "C" void kernel_launch(void* const* d_in, const int* in_sizes, int n_in,
                              void* d_out, int out_size, void* d_ws, size_t ws_size,
                              hipStream_t stream) {
    const float* x      = (const float*)d_in[0];
    const float* W_ih   = (const float*)d_in[1];
    const float* W_hh   = (const float*)d_in[2];
    const float* b_ih   = (const float*)d_in[3];
    const float* b_hh   = (const float*)d_in[4];
    const float* W_head = (const float*)d_in[5];
    const float* b_head = (const float*)d_in[6];
    float* out = (float*)d_out;

    const int B = in_sizes[0] / SEQ;            // 4096
    const int grid = B / WAVES_PER_BLOCK;       // 1024 blocks (1 batch/wave)

    lstm_fused_kernel<<<grid, BLOCK, 0, stream>>>(
        x, W_ih, W_hh, b_ih, b_hh, W_head, b_head, out);
}

// Round 3
// 527.952 us; speedup vs baseline: 1.0105x; 1.0105x over previous
//
#include <hip/hip_runtime.h>

#define HID 32
#define SEQ 512
#define WAVES_PER_BLOCK 4
#define BLOCK (WAVES_PER_BLOCK * 64)

#define LOG2E  1.4426950408889634f
#define LOG2E2 2.8853900817779268f

// broadcast lane `lane`'s value of v to all lanes via v_readlane (VALU pipe,
// SGPR result feeds v_fmac's scalar operand slot — no ds_bpermute)
__device__ __forceinline__ float bcastlane(float v, int lane) {
    return __int_as_float(__builtin_amdgcn_readlane(__float_as_int(v), lane));
}

// act(x) = 1 - m * rcp(1 + exp2(s*x)); sigmoid: m=1,s=log2e  tanh: m=2,s=2log2e
__device__ __forceinline__ float act_f(float x, float m, float s) {
    const float e = __builtin_amdgcn_exp2f(s * x);
    return __builtin_fmaf(-m, __builtin_amdgcn_rcpf(1.0f + e), 1.0f);
}

__global__
__attribute__((amdgpu_flat_work_group_size(BLOCK, BLOCK)))
__attribute__((amdgpu_waves_per_eu(4, 4)))   // pin: exactly 4 waves/EU -> 128-VGPR budget,
                                             // scheduler must NOT remat/spill for 8 waves
void lstm_fused_kernel(
    const float* __restrict__ x,       // [B, T, 1]
    const float* __restrict__ W_ih,    // [4H, 1]
    const float* __restrict__ W_hh,    // [4H, H] row-major
    const float* __restrict__ b_ih,    // [4H]
    const float* __restrict__ b_hh,    // [4H]
    const float* __restrict__ W_head,  // [1, H]
    const float* __restrict__ b_head,  // [1]
    float* __restrict__ out)           // [B, 1]
{
    const int tid  = threadIdx.x;
    const int lane = tid & 63;
    const int k    = lane & 31;   // hidden unit owned by this lane
    const int p    = lane >> 5;   // 0: rows (i, g)   1: rows (f, o)
    const int wave = tid >> 6;
    const int b    = blockIdx.x * WAVES_PER_BLOCK + wave;  // one batch per wave

    // gate-row ownership: rowA = lane (i-gate p=0, f-gate p=1),
    //                     rowB = 64+lane (g-gate p=0, o-gate p=1)
    const int rowA = lane;
    const int rowB = 64 + lane;

    // W_hh rows in VGPRs: 64 regs/lane, fits 128-VGPR budget @ 4 waves/EU
    float wA[HID], wB[HID];
    {
        const float4* WA4 = (const float4*)(W_hh + rowA * HID);
        const float4* WB4 = (const float4*)(W_hh + rowB * HID);
#pragma unroll
        for (int q = 0; q < HID / 4; ++q) {
            const float4 a = WA4[q], bb = WB4[q];
            wA[4*q+0] = a.x;  wA[4*q+1] = a.y;  wA[4*q+2] = a.z;  wA[4*q+3] = a.w;
            wB[4*q+0] = bb.x; wB[4*q+1] = bb.y; wB[4*q+2] = bb.z; wB[4*q+3] = bb.w;
        }
    }

    const float biasA = b_ih[rowA] + b_hh[rowA];
    const float biasB = b_ih[rowB] + b_hh[rowB];
    const float uA = W_ih[rowA];
    const float uB = W_ih[rowB];

    // gate A (i or f) is ALWAYS sigmoid. gate B: tanh on p=0 (g), sigmoid on p=1 (o).
    const float mB = p ? 1.0f  : 2.0f;
    const float sB = p ? LOG2E : LOG2E2;

    const float* xb = x + (size_t)b * SEQ;  // I == 1, wave-uniform pointer

    // real c,h live on p=1 lanes (lane 32+k holds unit k); p=0 copies are
    // garbage-but-bounded (never NaN: inf saturates through rcp(1+inf)=0)
    float h = 0.0f, c = 0.0f;

    for (int t = 0; t < SEQ; ++t) {
        const float xt = xb[t];  // wave-uniform -> scalar load
        float pA = __builtin_fmaf(xt, uA, biasA);
        float pB = __builtin_fmaf(xt, uB, biasB);
#pragma unroll
        for (int j = 0; j < HID; ++j) {
            const float hj = bcastlane(h, 32 + j);  // h_j lives on lane 32+j
            pA = __builtin_fmaf(hj, wA[j], pA);
            pB = __builtin_fmaf(hj, wB[j], pB);
        }
        const float actA = act_f(pA, 1.0f, LOG2E);  // sigmoid: i (p=0) / f (p=1)
        const float actB = act_f(pB, mB, sB);       // tanh g (p=0) / sigmoid o (p=1)

        // p=0 computes i*g locally; ship to p=1 (p=1's f*o arrives at p=0, unused)
        const float sw = __shfl_xor(actA * actB, 32);

        // on p=1: c = f*c + i*g ; h = o * tanh(c)
        c = __builtin_fmaf(actA, c, sw);
        const float tc = act_f(c, 2.0f, LOG2E2);
        h = actB * tc;
    }

    // head: h_k on lane 32+k -> mask p=0, reduce, lane 0 writes
    float v = p ? h * W_head[k] : 0.0f;
#pragma unroll
    for (int off = 32; off >= 1; off >>= 1)
        v += __shfl_xor(v, off);
    if (lane == 0) out[b] = v + b_head[0];
}

extern "C" void kernel_launch(void* const* d_in, const int* in_sizes, int n_in,
                              void* d_out, int out_size, void* d_ws, size_t ws_size,
                              hipStream_t stream) {
    const float* x      = (const float*)d_in[0];
    const float* W_ih   = (const float*)d_in[1];
    const float* W_hh   = (const float*)d_in[2];
    const float* b_ih   = (const float*)d_in[3];
    const float* b_hh   = (const float*)d_in[4];
    const float* W_head = (const float*)d_in[5];
    const float* b_head = (const float*)d_in[6];
    float* out = (float*)d_out;

    const int B = in_sizes[0] / SEQ;            // 4096
    const int grid = B / WAVES_PER_BLOCK;       // 1024 blocks, 1 batch per wave

    lstm_fused_kernel<<<grid, BLOCK, 0, stream>>>(
        x, W_ih, W_hh, b_ih, b_hh, W_head, b_head, out);
}

// Round 4
// 510.706 us; speedup vs baseline: 1.0446x; 1.0338x over previous
//
#include <hip/hip_runtime.h>

#define HID 32
#define SEQ 512
#define WAVES_PER_BLOCK 4
#define BLOCK (WAVES_PER_BLOCK * 64)

#define LOG2E  1.4426950408889634f
#define LOG2E2 2.8853900817779268f

// broadcast lane `lane`'s value of v to all lanes via v_readlane -> SGPR,
// feeds v_fmac's scalar operand slot (no ds_bpermute in the hot loop)
__device__ __forceinline__ float bcastlane(float v, int lane) {
    return __int_as_float(__builtin_amdgcn_readlane(__float_as_int(v), lane));
}

// act(x) = 1 - m * rcp(1 + exp2(s*x)); sigmoid: m=1,s=log2e  tanh: m=2,s=2log2e
// saturates cleanly at +/-inf (rcp(inf)=0), never NaN for finite x
__device__ __forceinline__ float act_f(float x, float m, float s) {
    const float e = __builtin_amdgcn_exp2f(s * x);
    return __builtin_fmaf(-m, __builtin_amdgcn_rcpf(1.0f + e), 1.0f);
}

__global__
__attribute__((amdgpu_flat_work_group_size(BLOCK, BLOCK)))
__attribute__((amdgpu_waves_per_eu(4, 4)))   // exactly 4 waves/EU -> 128-VGPR budget
void lstm_fused_kernel(
    const float* __restrict__ x,       // [B, T, 1]
    const float* __restrict__ W_ih,    // [4H, 1]
    const float* __restrict__ W_hh,    // [4H, H] row-major
    const float* __restrict__ b_ih,    // [4H]
    const float* __restrict__ b_hh,    // [4H]
    const float* __restrict__ W_head,  // [1, H]
    const float* __restrict__ b_head,  // [1]
    float* __restrict__ out)           // [B, 1]
{
    const int tid  = threadIdx.x;
    const int lane = tid & 63;
    const int k    = lane & 31;   // hidden unit owned by this lane
    const int p    = lane >> 5;   // 0: rows (i, g)   1: rows (f, o)
    const int wave = tid >> 6;
    const int b    = blockIdx.x * WAVES_PER_BLOCK + wave;  // one batch per wave

    // gate-row ownership: rowA = lane (i p=0 / f p=1), rowB = 64+lane (g / o)
    const int rowA = lane;
    const int rowB = 64 + lane;

    // ---- W_hh rows into VGPRs, then PIN so the allocator cannot sink the
    // loads back into the t-loop (rounds 2/3 showed it does exactly that).
    float wA[HID], wB[HID];
    {
        const float4* WA4 = (const float4*)(W_hh + rowA * HID);
        const float4* WB4 = (const float4*)(W_hh + rowB * HID);
#pragma unroll
        for (int q = 0; q < HID / 4; ++q) {
            const float4 a = WA4[q], bb = WB4[q];
            wA[4*q+0] = a.x;  wA[4*q+1] = a.y;  wA[4*q+2] = a.z;  wA[4*q+3] = a.w;
            wB[4*q+0] = bb.x; wB[4*q+1] = bb.y; wB[4*q+2] = bb.z; wB[4*q+3] = bb.w;
        }
    }
#pragma unroll
    for (int j = 0; j < HID; ++j) {
        asm volatile("" : "+v"(wA[j]));  // opaque def: no remat, must stay in a VGPR
        asm volatile("" : "+v"(wB[j]));
    }

    const float biasA = b_ih[rowA] + b_hh[rowA];
    const float biasB = b_ih[rowB] + b_hh[rowB];
    const float uA = W_ih[rowA];
    const float uB = W_ih[rowB];

    // gate A is ALWAYS sigmoid. gate B: tanh on p=0 (g), sigmoid on p=1 (o).
    const float mB = p ? 1.0f  : 2.0f;
    const float sB = p ? LOG2E : LOG2E2;

    // explicitly wave-uniform batch index -> x reads become s_load (SMEM pipe)
    const int b_s = __builtin_amdgcn_readfirstlane(b);
    const float* xb = x + (size_t)b_s * SEQ;  // I == 1

    // real c,h live on p=1 lanes (lane 32+k holds unit k); p=0 copies are
    // garbage-but-bounded (inf saturates through rcp -> never NaN)
    float h = 0.0f, c = 0.0f;

    for (int t = 0; t < SEQ; ++t) {
        const float xt = xb[t];  // uniform SGPR-based address -> scalar load
        float pA = __builtin_fmaf(xt, uA, biasA);
        float pB = __builtin_fmaf(xt, uB, biasB);
#pragma unroll
        for (int j = 0; j < HID; ++j) {
            const float hj = bcastlane(h, 32 + j);  // h_j lives on lane 32+j
            pA = __builtin_fmaf(hj, wA[j], pA);
            pB = __builtin_fmaf(hj, wB[j], pB);
        }
        const float actA = act_f(pA, 1.0f, LOG2E);  // sigmoid: i (p=0) / f (p=1)
        const float actB = act_f(pB, mB, sB);       // tanh g (p=0) / sigmoid o (p=1)

        // p=0 computes i*g locally; ship to p=1 (reverse direction unused)
        const float sw = __shfl_xor(actA * actB, 32);

        // on p=1 lanes: c = f*c + i*g ; h = o * tanh(c)
        c = __builtin_fmaf(actA, c, sw);
        const float tc = act_f(c, 2.0f, LOG2E2);
        h = actB * tc;
    }

    // head: h_k on lane 32+k -> mask p=0 half, reduce, lane 0 writes
    float v = p ? h * W_head[k] : 0.0f;
#pragma unroll
    for (int off = 32; off >= 1; off >>= 1)
        v += __shfl_xor(v, off);
    if (lane == 0) out[b] = v + b_head[0];
}

extern "C" void kernel_launch(void* const* d_in, const int* in_sizes, int n_in,
                              void* d_out, int out_size, void* d_ws, size_t ws_size,
                              hipStream_t stream) {
    const float* x      = (const float*)d_in[0];
    const float* W_ih   = (const float*)d_in[1];
    const float* W_hh   = (const float*)d_in[2];
    const float* b_ih   = (const float*)d_in[3];
    const float* b_hh   = (const float*)d_in[4];
    const float* W_head = (const float*)d_in[5];
    const float* b_head = (const float*)d_in[6];
    float* out = (float*)d_out;

    const int B = in_sizes[0] / SEQ;            // 4096
    const int grid = B / WAVES_PER_BLOCK;       // 1024 blocks, 1 batch per wave

    lstm_fused_kernel<<<grid, BLOCK, 0, stream>>>(
        x, W_ih, W_hh, b_ih, b_hh, W_head, b_head, out);
}

// Round 5
// 470.947 us; speedup vs baseline: 1.1328x; 1.0844x over previous
//
#include <hip/hip_runtime.h>

#define HID 32
#define SEQ 512
#define WAVES_PER_BLOCK 4
#define BLOCK (WAVES_PER_BLOCK * 64)

#define LOG2E  1.4426950408889634f
#define LOG2E2 2.8853900817779268f

// broadcast lane `lane`'s value of v via v_readlane -> SGPR operand of v_fmac
__device__ __forceinline__ float bcastlane(float v, int lane) {
    return __int_as_float(__builtin_amdgcn_readlane(__float_as_int(v), lane));
}

// act(x) = 1 - m * rcp(1 + exp2(s*x)); sigmoid: m=1,s=log2e  tanh: m=2,s=2log2e
// saturates cleanly at +/-inf (rcp(inf)=0), never NaN for finite x
__device__ __forceinline__ float act_f(float x, float m, float s) {
    const float e = __builtin_amdgcn_exp2f(s * x);
    return __builtin_fmaf(-m, __builtin_amdgcn_rcpf(1.0f + e), 1.0f);
}

__global__
__attribute__((amdgpu_flat_work_group_size(BLOCK, BLOCK)))
__attribute__((amdgpu_waves_per_eu(2, 2)))   // 2 waves/EU -> 256-VGPR budget:
                                             // give the allocator 2x headroom so
                                             // spilling 64 weight regs is clearly
                                             // unprofitable (R3/R4: at 128 budget
                                             // it spilled to scratch anyway)
void lstm_fused_kernel(
    const float* __restrict__ x,       // [B, T, 1]
    const float* __restrict__ W_ih,    // [4H, 1]
    const float* __restrict__ W_hh,    // [4H, H] row-major
    const float* __restrict__ b_ih,    // [4H]
    const float* __restrict__ b_hh,    // [4H]
    const float* __restrict__ W_head,  // [1, H]
    const float* __restrict__ b_head,  // [1]
    float* __restrict__ out)           // [B, 1]
{
    const int tid  = threadIdx.x;
    const int lane = tid & 63;
    const int k    = lane & 31;   // hidden unit owned by this lane
    const int p    = lane >> 5;   // 0: rows (i, g)   1: rows (f, o)
    const int wave = tid >> 6;
    const int b    = blockIdx.x * WAVES_PER_BLOCK + wave;  // one batch per wave

    // gate-row ownership: rowA = lane (i p=0 / f p=1), rowB = 64+lane (g / o)
    const int rowA = lane;
    const int rowB = 64 + lane;

    // W_hh rows into VGPRs (64 floats/lane) + opaque pin against remat
    float wA[HID], wB[HID];
    {
        const float4* WA4 = (const float4*)(W_hh + rowA * HID);
        const float4* WB4 = (const float4*)(W_hh + rowB * HID);
#pragma unroll
        for (int q = 0; q < HID / 4; ++q) {
            const float4 a = WA4[q], bb = WB4[q];
            wA[4*q+0] = a.x;  wA[4*q+1] = a.y;  wA[4*q+2] = a.z;  wA[4*q+3] = a.w;
            wB[4*q+0] = bb.x; wB[4*q+1] = bb.y; wB[4*q+2] = bb.z; wB[4*q+3] = bb.w;
        }
    }
#pragma unroll
    for (int j = 0; j < HID; ++j) {
        asm volatile("" : "+v"(wA[j]));
        asm volatile("" : "+v"(wB[j]));
    }

    const float biasA = b_ih[rowA] + b_hh[rowA];
    const float biasB = b_ih[rowB] + b_hh[rowB];
    const float uA = W_ih[rowA];
    const float uB = W_ih[rowB];

    // gate A is ALWAYS sigmoid. gate B: tanh on p=0 (g), sigmoid on p=1 (o).
    const float mB = p ? 1.0f  : 2.0f;
    const float sB = p ? LOG2E : LOG2E2;

    // wave-uniform batch index -> x reads go through the scalar (SMEM) pipe
    const int b_s = __builtin_amdgcn_readfirstlane(b);
    const float* xb = x + (size_t)b_s * SEQ;  // I == 1

    // real c,h live on p=1 lanes (lane 32+k holds unit k); p=0 copies are
    // garbage-but-bounded (inf saturates through rcp -> never NaN)
    float h = 0.0f, c = 0.0f;

    for (int t = 0; t < SEQ; ++t) {
        const float xt = xb[t];
        // 4 independent FMA chains (2 per gate) so 2 resident waves can
        // saturate the SIMD despite ~4-cyc dependent-fmac latency
        float pA0 = __builtin_fmaf(xt, uA, biasA), pA1 = 0.0f;
        float pB0 = __builtin_fmaf(xt, uB, biasB), pB1 = 0.0f;
#pragma unroll
        for (int j = 0; j < HID; j += 2) {
            const float hj0 = bcastlane(h, 32 + j);      // h_j lives on lane 32+j
            const float hj1 = bcastlane(h, 32 + j + 1);
            pA0 = __builtin_fmaf(hj0, wA[j],     pA0);
            pA1 = __builtin_fmaf(hj1, wA[j + 1], pA1);
            pB0 = __builtin_fmaf(hj0, wB[j],     pB0);
            pB1 = __builtin_fmaf(hj1, wB[j + 1], pB1);
        }
        const float pA = pA0 + pA1;
        const float pB = pB0 + pB1;

        const float actA = act_f(pA, 1.0f, LOG2E);  // sigmoid: i (p=0) / f (p=1)
        const float actB = act_f(pB, mB, sB);       // tanh g (p=0) / sigmoid o (p=1)

        // p=0 computes i*g locally; ship to p=1 (reverse direction unused)
        const float sw = __shfl_xor(actA * actB, 32);

        // on p=1 lanes: c = f*c + i*g ; h = o * tanh(c)
        c = __builtin_fmaf(actA, c, sw);
        const float tc = act_f(c, 2.0f, LOG2E2);
        h = actB * tc;
    }

    // head: h_k on lane 32+k -> mask p=0 half, reduce, lane 0 writes
    float v = p ? h * W_head[k] : 0.0f;
#pragma unroll
    for (int off = 32; off >= 1; off >>= 1)
        v += __shfl_xor(v, off);
    if (lane == 0) out[b] = v + b_head[0];
}

extern "C" void kernel_launch(void* const* d_in, const int* in_sizes, int n_in,
                              void* d_out, int out_size, void* d_ws, size_t ws_size,
                              hipStream_t stream) {
    const float* x      = (const float*)d_in[0];
    const float* W_ih   = (const float*)d_in[1];
    const float* W_hh   = (const float*)d_in[2];
    const float* b_ih   = (const float*)d_in[3];
    const float* b_hh   = (const float*)d_in[4];
    const float* W_head = (const float*)d_in[5];
    const float* b_head = (const float*)d_in[6];
    float* out = (float*)d_out;

    const int B = in_sizes[0] / SEQ;            // 4096
    const int grid = B / WAVES_PER_BLOCK;       // 1024 blocks, 1 batch per wave

    lstm_fused_kernel<<<grid, BLOCK, 0, stream>>>(
        x, W_ih, W_hh, b_ih, b_hh, W_head, b_head, out);
}